// Round 10
// baseline (918.043 us; speedup 1.0000x reference)
//
#include <hip/hip_runtime.h>
#include <math.h>

// ---------- constants ----------
#define Bc 4
#define Mc 4
#define Tc 128
#define Ec 512
#define Hc 2048
#define NEc 8
#define NSc 2
#define NHEADc 4
#define Pc 128
#define GRUHc 128
#define AKc 64
#define AVc 64
#define NTc 2048        // B*S
#define HDc 128         // E/NHEAD

typedef __bf16 bfv8 __attribute__((ext_vector_type(8)));
typedef float f32x4 __attribute__((ext_vector_type(4)));

// ---------------------------------------------------------------
// zero out/cnt + inline gWih transpose ([384][65] -> [65][384], exact
// fp32 move; merged here to save a graph node)
__global__ __launch_bounds__(256)
void zero_k(float* __restrict__ out, int* __restrict__ cnt,
            const float* __restrict__ gWih, float* __restrict__ gWihT)
{
    int i = blockIdx.x * 256 + threadIdx.x;
    float4* o4 = (float4*)out;
    if (i < (NTc * Ec) / 4) o4[i] = make_float4(0.f, 0.f, 0.f, 0.f);
    if (i < NEc) cnt[i] = 0;
    int j = i - (NTc * Ec) / 4;
    if (j >= 0 && j < 65 * 384) {
        int d = j / 384, g = j % 384;
        gWihT[j] = gWih[(size_t)g * 65 + d];
    }
}

// span zero (float4 granularity)
__global__ __launch_bounds__(256)
void zspan_k(float* __restrict__ p, int n4)
{
    int i = blockIdx.x * 256 + threadIdx.x;
    if (i < n4) ((float4*)p)[i] = make_float4(0.f, 0.f, 0.f, 0.f);
}

// ---------------------------------------------------------------
// batched tiled transpose + fp32->bf16 convert: W[K,N] -> Wt[N,K]
struct CJob { const float* src; __bf16* dst; };
struct CJobs8 { CJob j[8]; };

__global__ __launch_bounds__(256)
void convT_k(CJobs8 jobs, int K, int N)
{
    CJob J = jobs.j[blockIdx.z];
    __shared__ float t[32][33];
    int bx = blockIdx.x * 32;   // n tile
    int by = blockIdx.y * 32;   // k tile
    int tx = threadIdx.x & 31, ty = threadIdx.x >> 5;   // 32 x 8
#pragma unroll
    for (int i = 0; i < 4; ++i) {
        int k = by + ty + i * 8, n = bx + tx;
        t[ty + i * 8][tx] = (k < K && n < N) ? J.src[(size_t)k * N + n] : 0.f;
    }
    __syncthreads();
#pragma unroll
    for (int i = 0; i < 4; ++i) {
        int n = bx + ty + i * 8, k = by + tx;
        if (n < N && k < K) J.dst[(size_t)n * K + k] = (__bf16)t[tx][ty + i * 8];
    }
}

// ---------------------------------------------------------------
// fp32 tiled GEMM (router only — keeps top-2 routing bit-stable)
__global__ __launch_bounds__(256)
void gemm_k(const float* __restrict__ A, int lda,
            const float* __restrict__ B, int ldb,
            const float* __restrict__ bias,
            float* __restrict__ C, int ldc,
            int M, int N, int K, int relu)
{
    int tm = blockIdx.x * 64, tn = blockIdx.y * 64;
    if (tm >= M || tn >= N) return;
    __shared__ float As[16][68];
    __shared__ float Bs[16][68];
    int tid = threadIdx.x;
    int tx = tid & 15, ty = tid >> 4;
    float acc[4][4] = {};
    int arow = tid >> 2;
    int ak0  = (tid & 3) * 4;
    int bk   = tid >> 4;
    int bc0  = (tid & 15) * 4;
    int grA = tm + arow;
    const float* Arow = (grA < M) ? (A + (size_t)grA * lda) : nullptr;

    for (int k0 = 0; k0 < K; k0 += 16) {
#pragma unroll
        for (int u = 0; u < 4; ++u) {
            int k = k0 + ak0 + u;
            As[ak0 + u][arow] = (Arow && k < K) ? Arow[k] : 0.f;
        }
        int kb = k0 + bk;
#pragma unroll
        for (int u = 0; u < 4; ++u) {
            int n2 = tn + bc0 + u;
            Bs[bk][bc0 + u] = (kb < K && n2 < N) ? B[(size_t)kb * ldb + n2] : 0.f;
        }
        __syncthreads();
#pragma unroll
        for (int kk = 0; kk < 16; ++kk) {
            float a0 = As[kk][ty * 4 + 0], a1 = As[kk][ty * 4 + 1];
            float a2 = As[kk][ty * 4 + 2], a3 = As[kk][ty * 4 + 3];
            float b0 = Bs[kk][tx * 4 + 0], b1 = Bs[kk][tx * 4 + 1];
            float b2 = Bs[kk][tx * 4 + 2], b3 = Bs[kk][tx * 4 + 3];
            acc[0][0] += a0 * b0; acc[0][1] += a0 * b1; acc[0][2] += a0 * b2; acc[0][3] += a0 * b3;
            acc[1][0] += a1 * b0; acc[1][1] += a1 * b1; acc[1][2] += a1 * b2; acc[1][3] += a1 * b3;
            acc[2][0] += a2 * b0; acc[2][1] += a2 * b1; acc[2][2] += a2 * b2; acc[2][3] += a2 * b3;
            acc[3][0] += a3 * b0; acc[3][1] += a3 * b1; acc[3][2] += a3 * b2; acc[3][3] += a3 * b3;
        }
        __syncthreads();
    }
#pragma unroll
    for (int i = 0; i < 4; ++i) {
        int gr = tm + ty * 4 + i;
        if (gr >= M) continue;
#pragma unroll
        for (int j = 0; j < 4; ++j) {
            int gc = tn + tx * 4 + j;
            if (gc >= N) continue;
            float v = acc[i][j] + (bias ? bias[gc] : 0.f);
            if (relu) v = fmaxf(v, 0.f);
            C[(size_t)gr * ldc + gc] = v;
        }
    }
}

// ---------------------------------------------------------------
// batched bf16 MFMA GEMM with optional split-K.
// blockIdx.y encodes (ko, ny): ny = by % nTilesY, ko = by / nTilesY.
// Each chunk covers kIters BK=32 tiles. Bias applied only by ko==0
// (correct with atomic-accum / atomic-scatter epilogues).
// flags: 1=relu, 2=storeT, 4=storeBf, 8=atomicAccum(fp32 C).
struct GJob {
    const void* A;
    const void* B;
    const float* bias;
    void* C;
    const int* Mptr;
    const int* gatherA;
    float* scatterOut;
    const int* scatterList;
    const float* wvec;
    int ldc;
    int flags;
};
struct GJobs6 { GJob j[6]; };

#define LDA_S 40   // LDS row stride in bf16 elems (32 + 8 pad)
template<int AMODE>
__global__ __launch_bounds__(256)
void gemm_batch_k(GJobs6 jobs, int lda, int ldb, int N, int K,
                  int nTilesY, int kIters)
{
    GJob J = jobs.j[blockIdx.z];
    int M = *J.Mptr;
    int by = blockIdx.y;
    int ny = by % nTilesY, ko = by / nTilesY;
    int tm = blockIdx.x * 128, tn = ny * 128;
    if (tm >= M || tn >= N) return;
    int KT = K / 32;
    int kt0 = ko * kIters;
    int ktE = kt0 + kIters; if (ktE > KT) ktE = KT;
    if (kt0 >= KT) return;

    __shared__ __bf16 As[128 * LDA_S];
    __shared__ __bf16 Bs[128 * LDA_S];
    int tid = threadIdx.x, lane = tid & 63, wvi = tid >> 6;
    int wm = (wvi & 1) * 64, wn = (wvi >> 1) * 64;
    f32x4 acc[4][4] = {};

    int ar = tid >> 1, ah = (tid & 1) * 16;   // staging row / k-half
    const float*  Apf = nullptr;
    const __bf16* Apb = nullptr;
    if (tm + ar < M) {
        int g = J.gatherA ? J.gatherA[tm + ar] : (tm + ar);
        if (AMODE == 0) Apf = (const float*)J.A + (size_t)g * lda;
        else            Apb = (const __bf16*)J.A + (size_t)g * lda;
    }
    const __bf16* Bp = ((tn + ar) < N) ? ((const __bf16*)J.B + (size_t)(tn + ar) * ldb)
                                       : nullptr;

    float fa[16];
    bfv8 ra0, ra1, rb0, rb1;

    auto LOADA = [&](int k0) {
        int kb = k0 + ah;
        if (AMODE == 0) {
            if (Apf) {
                const float4* p = (const float4*)(Apf + kb);
                float4 x0 = p[0], x1 = p[1], x2 = p[2], x3 = p[3];
                fa[0]=x0.x; fa[1]=x0.y; fa[2]=x0.z; fa[3]=x0.w;
                fa[4]=x1.x; fa[5]=x1.y; fa[6]=x1.z; fa[7]=x1.w;
                fa[8]=x2.x; fa[9]=x2.y; fa[10]=x2.z; fa[11]=x2.w;
                fa[12]=x3.x; fa[13]=x3.y; fa[14]=x3.z; fa[15]=x3.w;
            } else {
#pragma unroll
                for (int i = 0; i < 16; ++i) fa[i] = 0.f;
            }
        } else {
            if (Apb) {
                ra0 = *(const bfv8*)(Apb + kb);
                ra1 = *(const bfv8*)(Apb + kb + 8);
            } else {
#pragma unroll
                for (int i = 0; i < 8; ++i) { ra0[i] = (__bf16)0.f; ra1[i] = (__bf16)0.f; }
            }
        }
    };
    auto LOADB = [&](int k0) {
        int kb = k0 + ah;
        if (Bp) {
            rb0 = *(const bfv8*)(Bp + kb);
            rb1 = *(const bfv8*)(Bp + kb + 8);
        } else {
#pragma unroll
            for (int i = 0; i < 8; ++i) { rb0[i] = (__bf16)0.f; rb1[i] = (__bf16)0.f; }
        }
    };

    LOADA(kt0 * 32);
    LOADB(kt0 * 32);

    for (int kt = kt0; kt < ktE; ++kt) {
        __syncthreads();
        if (AMODE == 0) {
            bfv8 p0, p1;
#pragma unroll
            for (int i = 0; i < 8; ++i) { p0[i] = (__bf16)fa[i]; p1[i] = (__bf16)fa[8 + i]; }
            *(bfv8*)(As + ar * LDA_S + ah) = p0;
            *(bfv8*)(As + ar * LDA_S + ah + 8) = p1;
        } else {
            *(bfv8*)(As + ar * LDA_S + ah) = ra0;
            *(bfv8*)(As + ar * LDA_S + ah + 8) = ra1;
        }
        *(bfv8*)(Bs + ar * LDA_S + ah) = rb0;
        *(bfv8*)(Bs + ar * LDA_S + ah + 8) = rb1;
        __syncthreads();
        if (kt + 1 < ktE) {
            LOADA((kt + 1) * 32);
            LOADB((kt + 1) * 32);
        }
        {
            int fr = lane & 15, quad = lane >> 4;
            bfv8 af[4], bfr[4];
            const __bf16* Ab = As + quad * 8 + fr * LDA_S;
            const __bf16* Bb2 = Bs + quad * 8 + fr * LDA_S;
#pragma unroll
            for (int t2 = 0; t2 < 4; ++t2) {
                af[t2]  = *(const bfv8*)(Ab + (wm + t2 * 16) * LDA_S);
                bfr[t2] = *(const bfv8*)(Bb2 + (wn + t2 * 16) * LDA_S);
            }
#pragma unroll
            for (int i = 0; i < 4; ++i)
#pragma unroll
                for (int j = 0; j < 4; ++j)
                    acc[i][j] = __builtin_amdgcn_mfma_f32_16x16x32_bf16(af[i], bfr[j], acc[i][j], 0, 0, 0);
        }
    }

    // epilogue: C layout col=lane&15, row=(lane>>4)*4+reg
    int col = lane & 15, rq = (lane >> 4) * 4;
    int relu = J.flags & 1, storeT = J.flags & 2, storeBf = J.flags & 4;
    int accum = J.flags & 8;
    int addBias = (J.bias != nullptr) && (ko == 0);
#pragma unroll
    for (int ti = 0; ti < 4; ++ti) {
#pragma unroll
        for (int tj = 0; tj < 4; ++tj) {
#pragma unroll
            for (int r = 0; r < 4; ++r) {
                int gm = tm + wm + ti * 16 + rq + r;
                int gn = tn + wn + tj * 16 + col;
                if (gm < M && gn < N) {
                    float v = acc[ti][tj][r] + (addBias ? J.bias[gn] : 0.f);
                    if (relu) v = fmaxf(v, 0.f);
                    if (J.scatterOut) {
                        int g = J.scatterList[gm];
                        atomicAdd(&J.scatterOut[(size_t)g * Ec + gn], v * J.wvec[(size_t)g * NEc]);
                    } else if (accum) {
                        atomicAdd(&((float*)J.C)[(size_t)gm * J.ldc + gn], v);
                    } else if (storeT) {
                        ((float*)J.C)[(size_t)gn * J.ldc + gm] = v;
                    } else if (storeBf) {
                        ((__bf16*)J.C)[(size_t)gm * J.ldc + gn] = (__bf16)v;
                    } else {
                        ((float*)J.C)[(size_t)gm * J.ldc + gn] = v;
                    }
                }
            }
        }
    }
}

// ---------------------------------------------------------------
// Flash attention over compacted tokens, batched over experts (blockIdx.z).
__global__ __launch_bounds__(256)
void flash_k(const float* __restrict__ QbB, const float* __restrict__ KbB,
             const float* __restrict__ VtB, float* __restrict__ AOB,
             const int* __restrict__ cntB)
{
    int e = blockIdx.z;
    const float* Qb = QbB + (size_t)e * NTc * Ec;
    const float* Kb = KbB + (size_t)e * NTc * Ec;
    const float* Vt = VtB + (size_t)e * NTc * Ec;
    float* AO = AOB + (size_t)e * NTc * Ec;
    int nv = cntB[e];
    int r0 = blockIdx.x * 64;
    if (r0 >= nv) return;
    int h = blockIdx.y;
    const int QS = 136, VS = 72;
    __shared__ __bf16 Ql[64 * 136];
    __shared__ __bf16 Kl[64 * 136];
    __shared__ __bf16 Vl[128 * 72];
    __shared__ __bf16 Pl[64 * 72];
    int tid = threadIdx.x, lane = tid & 63, wv = tid >> 6;
    int fr = lane & 15, quad = lane >> 4;

    {   // load Q tile (rows >= nv -> 0)
        int qr = tid >> 2, c0 = (tid & 3) * 32;
        const float* src = Qb + (size_t)(r0 + qr) * Ec + h * HDc + c0;
        __bf16* dst = Ql + qr * QS + c0;
        bool ok = (r0 + qr) < nv;
#pragma unroll
        for (int u = 0; u < 8; ++u) {
            float4 v = ok ? ((const float4*)src)[u] : make_float4(0.f, 0.f, 0.f, 0.f);
            dst[u*4+0] = (__bf16)v.x; dst[u*4+1] = (__bf16)v.y;
            dst[u*4+2] = (__bf16)v.z; dst[u*4+3] = (__bf16)v.w;
        }
    }

    f32x4 accO[8];
#pragma unroll
    for (int j = 0; j < 8; ++j) accO[j] = (f32x4){0.f, 0.f, 0.f, 0.f};
    float mrow[4] = {-1e30f, -1e30f, -1e30f, -1e30f};
    float lrow[4] = {0.f, 0.f, 0.f, 0.f};
    const float invsq = 0.08838834764831845f;   // 1/sqrt(128)

    for (int j0 = 0; j0 < nv; j0 += 64) {
        __syncthreads();
        {   // K tile
            int kr = tid >> 2, c0 = (tid & 3) * 32;
            const float* src = Kb + (size_t)(j0 + kr) * Ec + h * HDc + c0;
            __bf16* dst = Kl + kr * QS + c0;
            bool ok = (j0 + kr) < nv;
#pragma unroll
            for (int u = 0; u < 8; ++u) {
                float4 v = ok ? ((const float4*)src)[u] : make_float4(0.f, 0.f, 0.f, 0.f);
                dst[u*4+0] = (__bf16)v.x; dst[u*4+1] = (__bf16)v.y;
                dst[u*4+2] = (__bf16)v.z; dst[u*4+3] = (__bf16)v.w;
            }
        }
        {   // Vt tile (d-major)
            int dr = tid >> 1, c0 = (tid & 1) * 32;
            const float* src = Vt + (size_t)(h * HDc + dr) * NTc + j0 + c0;
            __bf16* dst = Vl + dr * VS + c0;
            int rem = nv - (j0 + c0);
            if (rem >= 32) {
#pragma unroll
                for (int u = 0; u < 8; ++u) {
                    float4 v = ((const float4*)src)[u];
                    dst[u*4+0] = (__bf16)v.x; dst[u*4+1] = (__bf16)v.y;
                    dst[u*4+2] = (__bf16)v.z; dst[u*4+3] = (__bf16)v.w;
                }
            } else {
                for (int u = 0; u < 32; ++u)
                    dst[u] = (u < rem) ? (__bf16)src[u] : (__bf16)0.f;
            }
        }
        __syncthreads();

        // S = Q K^T (wave owns rows wv*16..+16)
        f32x4 sc[4] = {};
#pragma unroll
        for (int ks = 0; ks < 4; ++ks) {
            bfv8 aq = *(const bfv8*)(Ql + (wv * 16 + fr) * QS + ks * 32 + quad * 8);
#pragma unroll
            for (int tj = 0; tj < 4; ++tj) {
                bfv8 bk8 = *(const bfv8*)(Kl + (tj * 16 + fr) * QS + ks * 32 + quad * 8);
                sc[tj] = __builtin_amdgcn_mfma_f32_16x16x32_bf16(aq, bk8, sc[tj], 0, 0, 0);
            }
        }

        float alpha[4];
#pragma unroll
        for (int r = 0; r < 4; ++r) {
            float sv[4];
            float mx = -1e30f;
#pragma unroll
            for (int tj = 0; tj < 4; ++tj) {
                float s = sc[tj][r] * invsq;
                bool valid = (j0 + tj * 16 + fr) < nv;
                s = valid ? s : -1e30f;
                sv[tj] = s;
                mx = fmaxf(mx, s);
            }
#pragma unroll
            for (int off = 1; off < 16; off <<= 1)
                mx = fmaxf(mx, __shfl_xor(mx, off, 64));
            float mn = fmaxf(mrow[r], mx);
            alpha[r] = expf(mrow[r] - mn);
            float ps = 0.f;
#pragma unroll
            for (int tj = 0; tj < 4; ++tj) {
                bool valid = (j0 + tj * 16 + fr) < nv;
                float p = valid ? expf(sv[tj] - mn) : 0.f;
                Pl[(wv * 16 + quad * 4 + r) * VS + tj * 16 + fr] = (__bf16)p;
                ps += p;
            }
#pragma unroll
            for (int off = 1; off < 16; off <<= 1)
                ps += __shfl_xor(ps, off, 64);
            lrow[r] = lrow[r] * alpha[r] + ps;
            mrow[r] = mn;
        }
#pragma unroll
        for (int tj = 0; tj < 8; ++tj)
#pragma unroll
            for (int r = 0; r < 4; ++r)
                accO[tj][r] *= alpha[r];
        // PV (P per-wave LDS region -> A frag; within-wave, no barrier)
#pragma unroll
        for (int ks = 0; ks < 2; ++ks) {
            bfv8 ap = *(const bfv8*)(Pl + (wv * 16 + fr) * VS + ks * 32 + quad * 8);
#pragma unroll
            for (int tj = 0; tj < 8; ++tj) {
                bfv8 bv8 = *(const bfv8*)(Vl + (tj * 16 + fr) * VS + ks * 32 + quad * 8);
                accO[tj] = __builtin_amdgcn_mfma_f32_16x16x32_bf16(ap, bv8, accO[tj], 0, 0, 0);
            }
        }
    }

#pragma unroll
    for (int r = 0; r < 4; ++r) {
        int row = r0 + wv * 16 + quad * 4 + r;
        if (row < nv) {
            float invl = 1.f / lrow[r];
#pragma unroll
            for (int tj = 0; tj < 8; ++tj)
                AO[(size_t)row * Ec + h * HDc + tj * 16 + fr] = accO[tj][r] * invl;
        }
    }
}

// ---------------------------------------------------------------
__global__ __launch_bounds__(256)
void router_ctx_k(const float* __restrict__ q4, const float* __restrict__ rR,
                  const float* __restrict__ rS,
                  const float* __restrict__ Wk, const float* __restrict__ bk,
                  const float* __restrict__ Wv, const float* __restrict__ bv,
                  float* __restrict__ ctx)
{
    int tid = threadIdx.x;
    int lane = tid & 63;
    int n = blockIdx.x * 4 + (tid >> 6);
    int m = (n >> 7) & 3, t = n & 127, b = n >> 9;
    float q = q4[(size_t)n * AKc + lane];
    float sc[3], rv[3], sv[3];
#pragma unroll
    for (int o = 0; o < 3; ++o) {
        int oth = o + (o >= m ? 1 : 0);
        float r = rR[(((size_t)(b * Mc + m)) * Mc + oth) * Tc + t];
        float s_ = rS[(((size_t)(b * Mc + m)) * Mc + oth) * Tc + t];
        rv[o] = r; sv[o] = s_;
        float key = r * Wk[lane] + s_ * Wk[64 + lane] + bk[lane];
        float p = q * key;
#pragma unroll
        for (int off = 32; off; off >>= 1) p += __shfl_xor(p, off, 64);
        sc[o] = p * 0.125f;
    }
    float mx = fmaxf(sc[0], fmaxf(sc[1], sc[2]));
    float e0 = expf(sc[0] - mx), e1 = expf(sc[1] - mx), e2 = expf(sc[2] - mx);
    float inv = 1.f / (e0 + e1 + e2);
    float p0 = e0 * inv, p1 = e1 * inv, p2 = e2 * inv;
    float v0 = rv[0] * Wv[lane] + sv[0] * Wv[64 + lane] + bv[lane];
    float v1 = rv[1] * Wv[lane] + sv[1] * Wv[64 + lane] + bv[lane];
    float v2 = rv[2] * Wv[lane] + sv[2] * Wv[64 + lane] + bv[lane];
    ctx[(size_t)n * AVc + lane] = p0 * v0 + p1 * v1 + p2 * v2;
}

// ---------------------------------------------------------------
// gi_k v2: coalesced weight access via pre-transposed WT[65][384]
// (r9 win: 935.7 -> 913.4us). Accumulation order identical to v1.
__global__ __launch_bounds__(384)
void gi_k(const float* __restrict__ rU, const float* __restrict__ ctx,
          const float* __restrict__ WT, const float* __restrict__ gbih,
          float* __restrict__ gi)
{
    int nt = blockIdx.x;            // 2048
    int g = threadIdx.x;            // 384
    __shared__ float cl[64];
    if (g < 64) cl[g] = ctx[(size_t)nt * AVc + g];
    __syncthreads();
    float a = gbih[g] + rU[nt] * WT[g];
#pragma unroll
    for (int d = 0; d < 64; ++d) a += cl[d] * WT[(size_t)(1 + d) * 384 + g];
    gi[(size_t)nt * 384 + g] = a;
}

// ---------------------------------------------------------------
// GRU scan — FROZEN at the r7 version (best measured: 114us).
__device__ __forceinline__ void wgbar()
{
    __builtin_amdgcn_sched_barrier(0);
    asm volatile("s_waitcnt lgkmcnt(0)" ::: "memory");
    __builtin_amdgcn_s_barrier();
    __builtin_amdgcn_sched_barrier(0);
}

__global__ __launch_bounds__(1024) __attribute__((amdgpu_waves_per_eu(4, 4)))
void gru_scan_k(const float* __restrict__ gi, const float* __restrict__ gWhh,
                const float* __restrict__ gbhh, float* __restrict__ hs)
{
    int seq = blockIdx.x, tid = threadIdx.x;
    int work = (tid < 768);
    int g = work ? (tid >> 1) : 0;           // output g (safe for idle waves)
    int half = tid & 1;                      // K-half
    __shared__ float h[136];                 // [0..63] half0, [68..131] half1
    __shared__ float gh[384];
    const f32x4* wp = (const f32x4*)(gWhh + (size_t)g * 128 + half * 64);
    f32x4 w0 = wp[0],  w1 = wp[1],  w2 = wp[2],  w3 = wp[3];
    f32x4 w4 = wp[4],  w5 = wp[5],  w6 = wp[6],  w7 = wp[7];
    f32x4 w8 = wp[8],  w9 = wp[9],  wA = wp[10], wB = wp[11];
    f32x4 wC = wp[12], wD = wp[13], wE = wp[14], wF = wp[15];
    float bh = gbhh[g];

    // gate state (threads 0..127 = waves 0,1)
    float hreg = 0.f, c0 = 0.f, c1 = 0.f, c2 = 0.f;
    int hi = tid + ((tid >> 6) << 2);        // tid<64 -> tid; 64..127 -> tid+4
    if (tid < 128) {
        h[hi] = 0.f;
        const float* gr = gi + (size_t)seq * 128 * 384;
        c0 = gr[tid]; c1 = gr[128 + tid]; c2 = gr[256 + tid];
    }
    wgbar();

    for (int t = 0; t < 128; ++t) {
        // keep weights resident: 4-reg vector granules, pinned every iter
        asm volatile("" : "+v"(w0), "+v"(w1), "+v"(w2), "+v"(w3),
                          "+v"(w4), "+v"(w5), "+v"(w6), "+v"(w7),
                          "+v"(w8), "+v"(w9), "+v"(wA), "+v"(wB),
                          "+v"(wC), "+v"(wD), "+v"(wE), "+v"(wF));
        // prefetch gi row for t+1 — full matvec of latency cover
        float n0 = 0.f, n1 = 0.f, n2 = 0.f;
        if (tid < 128 && t + 1 < 128) {
            const float* gr = gi + ((size_t)seq * 128 + t + 1) * 384;
            n0 = gr[tid]; n1 = gr[128 + tid]; n2 = gr[256 + tid];
        }
        if (work) {
            // half dot product: 64 FMAs over the thread's h-half
            float a0 = 0.f, a1 = 0.f, a2 = 0.f, a3 = 0.f;
            const float* hb = h + half * 68; // conflict-free bank offset
#define GRU_STEP4(W, B) { \
            f32x4 x = *(const f32x4*)&hb[B]; \
            a0 += x[0] * W[0]; a1 += x[1] * W[1]; a2 += x[2] * W[2]; a3 += x[3] * W[3]; }
            GRU_STEP4(w0, 0)   GRU_STEP4(w1, 4)   GRU_STEP4(w2, 8)   GRU_STEP4(w3, 12)
            GRU_STEP4(w4, 16)  GRU_STEP4(w5, 20)  GRU_STEP4(w6, 24)  GRU_STEP4(w7, 28)
            GRU_STEP4(w8, 32)  GRU_STEP4(w9, 36)  GRU_STEP4(wA, 40)  GRU_STEP4(wB, 44)
            GRU_STEP4(wC, 48)  GRU_STEP4(wD, 52)  GRU_STEP4(wE, 56)  GRU_STEP4(wF, 60)
#undef GRU_STEP4
            float s = (a0 + a1) + (a2 + a3);
            s += __shfl_xor(s, 1, 64);       // combine the two K-halves
            if (half == 0) gh[g] = s + bh;
        }
        wgbar();                              // no vmcnt drain
        if (tid < 128) {
            float ghr = gh[tid], ghz = gh[128 + tid], ghn = gh[256 + tid];
            float r  = 1.f / (1.f + expf(-(c0 + ghr)));
            float z  = 1.f / (1.f + expf(-(c1 + ghz)));
            float nn = tanhf(c2 + r * ghn);
            float hn = (1.f - z) * nn + z * hreg;
            hs[((size_t)seq * 128 + t) * 128 + tid] = hn;   // fire-and-forget
            h[hi] = hn;
            hreg = hn;
            c0 = n0; c1 = n1; c2 = n2;        // vmcnt wait lands here only
        }
        wgbar();
    }
}

// ---------------------------------------------------------------
__global__ __launch_bounds__(128)
void mlp_route_k(const float* __restrict__ proc, const float* __restrict__ hs,
                 const float* __restrict__ mW1, const float* __restrict__ mb1,
                 const float* __restrict__ mW2, const float* __restrict__ mb2,
                 float* __restrict__ probsOut, float* __restrict__ idxOut,
                 float* __restrict__ w)
{
    int n = blockIdx.x, tid = threadIdx.x;
    __shared__ float comb[256], tmp[128], lg[8];
    comb[tid] = proc[(size_t)n * 128 + tid];
    comb[128 + tid] = hs[(size_t)n * 128 + tid];
    __syncthreads();
    float a = mb1[tid];
#pragma unroll 8
    for (int d = 0; d < 256; ++d) a += comb[d] * mW1[(size_t)d * 128 + tid];
    tmp[tid] = fmaxf(a, 0.f);
    __syncthreads();
    if (tid < 8) {
        float l = mb2[tid];
        for (int d = 0; d < 128; ++d) l += tmp[d] * mW2[(size_t)d * 8 + tid];
        lg[tid] = l;
    }
    __syncthreads();
    if (tid == 0) {
        float mx = lg[0];
        for (int e = 1; e < 8; ++e) mx = fmaxf(mx, lg[e]);
        float p[8], s = 0.f;
        for (int e = 0; e < 8; ++e) { p[e] = expf(lg[e] - mx); s += p[e]; }
        float inv = 1.f / s;
        for (int e = 0; e < 8; ++e) probsOut[(size_t)n * 8 + e] = p[e] * inv;
        int a0 = 0; float v0 = lg[0];
        for (int e = 1; e < 8; ++e) if (lg[e] > v0) { v0 = lg[e]; a0 = e; }
        int a1 = -1; float v1 = -1e30f;
        for (int e = 0; e < 8; ++e) if (e != a0 && lg[e] > v1) { v1 = lg[e]; a1 = e; }
        float e1 = expf(v1 - v0);
        float t0 = 1.f / (1.f + e1), t1 = e1 / (1.f + e1);
        idxOut[(size_t)n * 2 + 0] = (float)a0;
        idxOut[(size_t)n * 2 + 1] = (float)a1;
        for (int e = 0; e < 8; ++e) w[(size_t)n * 8 + e] = 0.f;
        w[(size_t)n * 8 + a0] = t0;
        w[(size_t)n * 8 + a1] = t1;
    }
}

__global__ __launch_bounds__(256)
void compact_k(const float* __restrict__ w, int* __restrict__ cnt,
               int* __restrict__ list)
{
    int n = blockIdx.x * 256 + threadIdx.x;
    if (n >= NTc) return;
    for (int e = 0; e < NEc; ++e)
        if (w[(size_t)n * 8 + e] > 0.f) {
            int p = atomicAdd(&cnt[e], 1);
            list[e * NTc + p] = n;
        }
}

// ---------------------------------------------------------------
// LN1 batched over experts (blockIdx.y): LN(x[list[i]] + PRJ[i]) -> H1[i]
__global__ __launch_bounds__(256)
void ln1_k(const float* __restrict__ x, const int* __restrict__ listB,
           const float* __restrict__ addB, const float* __restrict__ sB,
           const float* __restrict__ bB, float* __restrict__ outB,
           const int* __restrict__ cntB)
{
    int e = blockIdx.y;
    int i = blockIdx.x;
    if (i >= cntB[e]) return;
    const int* list = listB + e * NTc;
    const float* add = addB + (size_t)e * NTc * Ec;
    const float* s = sB + e * Ec;
    const float* b = bB + e * Ec;
    float* outRows = outB + (size_t)e * NTc * Ec;
    int tid = threadIdx.x;
    int g = list[i];
    float v0 = x[(size_t)g * Ec + tid] + add[(size_t)i * Ec + tid];
    float v1 = x[(size_t)g * Ec + 256 + tid] + add[(size_t)i * Ec + 256 + tid];
    __shared__ float red[256];
    __shared__ float bc;
    red[tid] = v0 + v1; __syncthreads();
    for (int st = 128; st > 0; st >>= 1) { if (tid < st) red[tid] += red[tid + st]; __syncthreads(); }
    if (tid == 0) bc = red[0] * (1.f / 512.f);
    __syncthreads();
    float mu = bc;
    float d0 = v0 - mu, d1 = v1 - mu;
    __syncthreads();
    red[tid] = d0 * d0 + d1 * d1; __syncthreads();
    for (int st = 128; st > 0; st >>= 1) { if (tid < st) red[tid] += red[tid + st]; __syncthreads(); }
    if (tid == 0) bc = rsqrtf(red[0] * (1.f / 512.f) + 1e-5f);
    __syncthreads();
    float inv = bc;
    outRows[(size_t)i * Ec + tid] = d0 * inv * s[tid] + b[tid];
    outRows[(size_t)i * Ec + 256 + tid] = d1 * inv * s[256 + tid] + b[256 + tid];
}

// LN2 batched over experts; atomic scatter (experts' token sets overlap)
__global__ __launch_bounds__(256)
void ln2_scatter_k(const float* __restrict__ H1B, const float* __restrict__ YB,
                   const float* __restrict__ sB, const float* __restrict__ bB,
                   float* __restrict__ out, const int* __restrict__ listB,
                   const int* __restrict__ cntB, const float* __restrict__ wB)
{
    int e = blockIdx.y;
    int i = blockIdx.x;
    if (i >= cntB[e]) return;
    const int* list = listB + e * NTc;
    const float* H1 = H1B + (size_t)e * NTc * Ec;
    const float* Y = YB + (size_t)e * NTc * Ec;
    const float* s = sB + e * Ec;
    const float* b = bB + e * Ec;
    const float* wvec = wB + e;
    int tid = threadIdx.x;
    int g = list[i];
    float v0 = H1[(size_t)i * Ec + tid] + Y[(size_t)i * Ec + tid];
    float v1 = H1[(size_t)i * Ec + 256 + tid] + Y[(size_t)i * Ec + 256 + tid];
    __shared__ float red[256];
    __shared__ float bc;
    red[tid] = v0 + v1; __syncthreads();
    for (int st = 128; st > 0; st >>= 1) { if (tid < st) red[tid] += red[tid + st]; __syncthreads(); }
    if (tid == 0) bc = red[0] * (1.f / 512.f);
    __syncthreads();
    float mu = bc;
    float d0 = v0 - mu, d1 = v1 - mu;
    __syncthreads();
    red[tid] = d0 * d0 + d1 * d1; __syncthreads();
    for (int st = 128; st > 0; st >>= 1) { if (tid < st) red[tid] += red[tid + st]; __syncthreads(); }
    if (tid == 0) bc = rsqrtf(red[0] * (1.f / 512.f) + 1e-5f);
    __syncthreads();
    float inv = bc;
    float wv = wvec[(size_t)g * 8];
    atomicAdd(&out[(size_t)g * Ec + tid], (d0 * inv * s[tid] + b[tid]) * wv);
    atomicAdd(&out[(size_t)g * Ec + 256 + tid], (d1 * inv * s[256 + tid] + b[256 + tid]) * wv);
}

// ---------------------------------------------------------------
extern "C" void kernel_launch(void* const* d_in, const int* in_sizes, int n_in,
                              void* d_out, int out_size, void* d_ws, size_t ws_size,
                              hipStream_t stream)
{
    const float* x    = (const float*)d_in[0];
    const float* rU   = (const float*)d_in[1];
    const float* rR   = (const float*)d_in[2];
    const float* rS   = (const float*)d_in[3];
    const float* Wtp  = (const float*)d_in[6];
    const float* btp  = (const float*)d_in[7];
    const float* Wq   = (const float*)d_in[8];
    const float* bq   = (const float*)d_in[9];
    const float* Wk   = (const float*)d_in[10];
    const float* bk   = (const float*)d_in[11];
    const float* Wv   = (const float*)d_in[12];
    const float* bv   = (const float*)d_in[13];
    const float* gWih = (const float*)d_in[14];
    const float* gbih = (const float*)d_in[15];
    const float* gWhh = (const float*)d_in[16];
    const float* gbhh = (const float*)d_in[17];
    const float* mW1  = (const float*)d_in[18];
    const float* mb1  = (const float*)d_in[19];
    const float* mW2  = (const float*)d_in[20];
    const float* mb2  = (const float*)d_in[21];
    const float* sWq  = (const float*)d_in[22];
    const float* sbq  = (const float*)d_in[23];
    const float* sWk  = (const float*)d_in[24];
    const float* sbk  = (const float*)d_in[25];
    const float* sWv  = (const float*)d_in[26];
    const float* sbv  = (const float*)d_in[27];
    const float* sWo  = (const float*)d_in[28];
    const float* sbo  = (const float*)d_in[29];
    const float* sln1s = (const float*)d_in[30];
    const float* sln1b = (const float*)d_in[31];
    const float* sW1  = (const float*)d_in[32];
    const float* sb1  = (const float*)d_in[33];
    const float* sW2  = (const float*)d_in[34];
    const float* sb2  = (const float*)d_in[35];
    const float* sln2s = (const float*)d_in[36];
    const float* sln2b = (const float*)d_in[37];
    const float* fW1  = (const float*)d_in[38];
    const float* fb1  = (const float*)d_in[39];
    const float* fW2  = (const float*)d_in[40];
    const float* fb2  = (const float*)d_in[41];

    float* out      = (float*)d_out;                 // [2048,512]
    float* probsOut = out + (size_t)NTc * Ec;        // [2048,8]
    float* idxOut   = probsOut + (size_t)NTc * NEc;  // [2048,2]

    // ---- workspace layout ----
    int*   cnt  = (int*)d_ws;                        // 64 ints
    int*   list = cnt + 64;                          // 8*2048
    float* w    = (float*)d_ws + 64 + NEc * NTc;     // [2048,8]
    __bf16* WB = (__bf16*)(w + NTc * NEc);
    auto QKVO_T = [&](int e, int i) { return WB + ((size_t)(e * 4 + i)) * 262144; };
    __bf16* sW1T = WB + 8 * 262144;            // 2 x [2048][512]
    __bf16* sW2T = sW1T + 2 * 1048576;         // 2 x [512][2048]
    __bf16* fW1T = sW2T + 2 * 1048576;         // 3 x [2048][512] (round 1)
    __bf16* fW2T = fW1T + 3 * 1048576;         // 3 x [512][2048] (round 1)
    float* act = (float*)(fW2T + 3 * 1048576);
    float* QbB = act;                          // 2 x [2048][512]
    float* KbB = act + 2 * 1048576;            // 2 x
    float* VtB = act + 4 * 1048576;            // 2 x [512][2048] d-major
    float* AOB = act + 6 * 1048576;            // 2 x
    float* H1B = act + 8 * 1048576;            // 2 x
    float* PRJB = QbB;                         // alias (Qb dead after flash)
    float* YbB  = KbB;                         // alias (Kb dead after flash)
    __bf16* FF1syn = (__bf16*)VtB;             // 2 x [2048][2048] bf16 (Vt/AO dead)
    __bf16* FF1ffn = (__bf16*)act;             // 3 x [2048][2048] bf16 (FFN phase)
    // round-2 FFN weights live in the act tail (free once synergy is done):
    __bf16* fW1T2 = FF1ffn + (size_t)3 * NTc * Hc;   // 3 x [2048][512]
    __bf16* fW2T2 = fW1T2 + 3 * 1048576;             // 3 x [512][2048]
    // router region overlays act (dead before experts start)
    float* proc = act;                 // 2048*128
    float* q4   = act + 262144;
    float* ctx  = act + 393216;
    float* gi   = act + 524288;        // 16*128*384
    float* hs   = act + 1310720;       // 2048*128
    float* gWihT = act + 1572864;      // [65][384] fp32 (dead region during router)

    // ---- init (zero + gWih transpose fused) ----
    zero_k<<<1122, 256, 0, stream>>>(out, cnt, gWih, gWihT);

    // ---- router (fp32 — keeps top-2 idx bit-stable) ----
    gemm_k<<<dim3(32, 2), 256, 0, stream>>>(x, Ec, Wtp, Pc, btp, proc, Pc, NTc, Pc, Ec, 1);
    gemm_k<<<dim3(32, 1), 256, 0, stream>>>(proc, Pc, Wq, AKc, bq, q4, AKc, NTc, AKc, Pc, 0);
    router_ctx_k<<<512, 256, 0, stream>>>(q4, rR, rS, Wk, bk, Wv, bv, ctx);
    gi_k<<<2048, 384, 0, stream>>>(rU, ctx, gWihT, gbih, gi);
    gru_scan_k<<<16, 1024, 0, stream>>>(gi, gWhh, gbhh, hs);
    mlp_route_k<<<2048, 128, 0, stream>>>(proc, hs, mW1, mb1, mW2, mb2,
                                          probsOut, idxOut, w);
    compact_k<<<8, 256, 0, stream>>>(w, cnt, list);

    GJob JZ = {};

    // ---- synergy weight conversion (3 dispatches) ----
    {
        CJobs8 cq = {};
        for (int e = 0; e < 2; ++e) {
            cq.j[e * 4 + 0] = { sWq + (size_t)e * Ec * Ec, QKVO_T(e, 0) };
            cq.j[e * 4 + 1] = { sWk + (size_t)e * Ec * Ec, QKVO_T(e, 1) };
            cq.j[e * 4 + 2] = { sWv + (size_t)e * Ec * Ec, QKVO_T(e, 2) };
            cq.j[e * 4 + 3] = { sWo + (size_t)e * Ec * Ec, QKVO_T(e, 3) };
        }
        convT_k<<<dim3(16, 16, 8), 256, 0, stream>>>(cq, Ec, Ec);
        CJobs8 c1 = {};
        c1.j[0] = { sW1, sW1T };
        c1.j[1] = { sW1 + (size_t)Ec * Hc, sW1T + 1048576 };
        convT_k<<<dim3(64, 16, 2), 256, 0, stream>>>(c1, Ec, Hc);
        CJobs8 c2 = {};
        c2.j[0] = { sW2, sW2T };
        c2.j[1] = { sW2 + (size_t)Hc * Ec, sW2T + 1048576 };
        convT_k<<<dim3(16, 64, 2), 256, 0, stream>>>(c2, Hc, Ec);
    }

    // ---- QKV for both experts: one 6-job dispatch ----
    {
        GJobs6 js = {};
        for (int e = 0; e < 2; ++e) {
            GJob jq = JZ;
            jq.A = x; jq.Mptr = cnt + e; jq.gatherA = list + e * NTc;
            jq.B = QKVO_T(e, 0); jq.bias = sbq + e * Ec;
            jq.C = QbB + (size_t)e * NTc * Ec; jq.ldc = Ec; jq.flags = 0;
            GJob jk = jq; jk.B = QKVO_T(e, 1); jk.bias = sbk + e * Ec;
            jk.C = KbB + (size_t)e * NTc * Ec;
            GJob jv = jq; jv.B = QKVO_T(e, 2); jv.bias = sbv + e * Ec;
            jv.C = VtB + (size_t)e * NTc * Ec; jv.ldc = NTc; jv.flags = 2;
            js.j[e * 3 + 0] = jq; js.j[e * 3 + 1] = jk; js.j[e * 3 + 2] = jv;
        }
        gemm_batch_k<0><<<dim3(16, 4, 6), 256, 0, stream>>>(js, Ec, Ec, Ec, Ec, 4, 16);
    }

    // ---- flash attention, both experts ----
    flash_k<<<dim3(32, 4, 2), 256, 0, stream>>>(QbB, KbB, VtB, AOB, cnt);

    // ---- zero PRJB+YbB (aliases Qb/Kb, dead after flash) for split-K accum ----
    zspan_k<<<4096, 256, 0, stream>>>(act, 1048576);   // 4M floats = 16MB

    // ---- Wo projection, both experts: split-K x4 (atomic accum) ----
    {
        GJobs6 js = {};
        for (int e = 0; e < 2; ++e) {
            GJob jo = JZ;
            jo.A = AOB + (size_t)e * NTc * Ec; jo.Mptr = cnt + e;
            jo.B = QKVO_T(e, 3); jo.bias = sbo + e * Ec;
            jo.C = PRJB + (size_t)e * NTc * Ec; jo.ldc = Ec; jo.flags = 8;
            js.j[e] = jo;
        }
        gemm_batch_k<0><<<dim3(16, 16, 2), 256, 0, stream>>>(js, Ec, Ec, Ec, Ec, 4, 4);
    }

    // ---- LN1, both experts ----
    ln1_k<<<dim3(2048, 2), 256, 0, stream>>>(x, list, PRJB, sln1s, sln1b, H1B, cnt);

    // ---- FF1 (relu, bf16 out), both experts ----
    {
        GJobs6 js = {};
        for (int e = 0; e < 2; ++e) {
            GJob j1 = JZ;
            j1.A = H1B + (size_t)e * NTc * Ec; j1.Mptr = cnt + e;
            j1.B = sW1T + (size_t)e * 1048576; j1.bias = sb1 + (size_t)e * Hc;
            j1.C = FF1syn + (size_t)e * NTc * Hc; j1.ldc = Hc; j1.flags = 1 | 4;
            js.j[e] = j1;
        }
        gemm_batch_k<0><<<dim3(16, 16, 2), 256, 0, stream>>>(js, Ec, Ec, Hc, Ec, 16, 16);
    }

    // ---- FF2 (bf16 A), both experts: split-K x4 (atomic accum into zeroed YbB) ----
    {
        GJobs6 js = {};
        for (int e = 0; e < 2; ++e) {
            GJob j2 = JZ;
            j2.A = FF1syn + (size_t)e * NTc * Hc; j2.Mptr = cnt + e;
            j2.B = sW2T + (size_t)e * 1048576; j2.bias = sb2 + (size_t)e * Ec;
            j2.C = YbB + (size_t)e * NTc * Ec; j2.ldc = Ec; j2.flags = 8;
            js.j[e] = j2;
        }
        gemm_batch_k<1><<<dim3(16, 16, 2), 256, 0, stream>>>(js, Hc, Hc, Ec, Hc, 4, 16);
    }

    // ---- LN2 + weighted scatter (atomic), both experts ----
    ln2_scatter_k<<<dim3(2048, 2), 256, 0, stream>>>(H1B, YbB, sln2s, sln2b,
                                                     out, list, cnt, w);

    // ---- FFN experts: all 6 weight conversions upfront (2 dispatches) ----
    {
        CJobs8 a = {};
        for (int u = 0; u < 6; ++u)
            a.j[u] = { fW1 + (size_t)u * Ec * Hc,
                       (u < 3 ? fW1T + (size_t)u * 1048576
                              : fW1T2 + (size_t)(u - 3) * 1048576) };
        convT_k<<<dim3(64, 16, 6), 256, 0, stream>>>(a, Ec, Hc);
        CJobs8 b = {};
        for (int u = 0; u < 6; ++u)
            b.j[u] = { fW2 + (size_t)u * Hc * Ec,
                       (u < 3 ? fW2T + (size_t)u * 1048576
                              : fW2T2 + (size_t)(u - 3) * 1048576) };
        convT_k<<<dim3(16, 64, 6), 256, 0, stream>>>(b, Hc, Ec);
    }

    // ---- FFN GEMMs: 2 rounds of 3 ----
    for (int rnd = 0; rnd < 2; ++rnd) {
        int f0 = rnd * 3;
        __bf16* W1 = rnd == 0 ? fW1T : fW1T2;
        __bf16* W2 = rnd == 0 ? fW2T : fW2T2;
        {
            GJobs6 js = {};
            for (int u = 0; u < 3; ++u) {
                int f = f0 + u, e = f + NSc;
                GJob j1 = JZ;
                j1.A = x; j1.Mptr = cnt + e; j1.gatherA = list + e * NTc;
                j1.B = W1 + (size_t)u * 1048576; j1.bias = fb1 + (size_t)f * Hc;
                j1.C = FF1ffn + (size_t)u * NTc * Hc; j1.ldc = Hc; j1.flags = 1 | 4;
                js.j[u] = j1;
            }
            gemm_batch_k<0><<<dim3(16, 16, 3), 256, 0, stream>>>(js, Ec, Ec, Hc, Ec, 16, 16);
        }
        {
            // FF2 scatter with split-K: 4 chunks of 16 k-iters (K=2048)
            GJobs6 js = {};
            for (int u = 0; u < 3; ++u) {
                int f = f0 + u, e = f + NSc;
                GJob j2 = JZ;
                j2.A = FF1ffn + (size_t)u * NTc * Hc; j2.Mptr = cnt + e;
                j2.B = W2 + (size_t)u * 1048576; j2.bias = fb2 + (size_t)f * Ec;
                j2.scatterOut = out; j2.scatterList = list + e * NTc;
                j2.wvec = w + e; j2.ldc = Ec;
                js.j[u] = j2;
            }
            gemm_batch_k<1><<<dim3(16, 16, 3), 256, 0, stream>>>(js, Hc, Hc, Ec, Hc, 4, 16);
        }
    }
}

// Round 11
// 878.243 us; speedup vs baseline: 1.0453x; 1.0453x over previous
//
#include <hip/hip_runtime.h>
#include <math.h>

// ---------- constants ----------
#define Bc 4
#define Mc 4
#define Tc 128
#define Ec 512
#define Hc 2048
#define NEc 8
#define NSc 2
#define NHEADc 4
#define Pc 128
#define GRUHc 128
#define AKc 64
#define AVc 64
#define NTc 2048        // B*S
#define HDc 128         // E/NHEAD

typedef __bf16 bfv8 __attribute__((ext_vector_type(8)));
typedef float f32x4 __attribute__((ext_vector_type(4)));

// ---------------------------------------------------------------
// zero out/cnt + inline gWih transpose ([384][65] -> [65][384])
__global__ __launch_bounds__(256)
void zero_k(float* __restrict__ out, int* __restrict__ cnt,
            const float* __restrict__ gWih, float* __restrict__ gWihT)
{
    int i = blockIdx.x * 256 + threadIdx.x;
    float4* o4 = (float4*)out;
    if (i < (NTc * Ec) / 4) o4[i] = make_float4(0.f, 0.f, 0.f, 0.f);
    if (i < NEc) cnt[i] = 0;
    int j = i - (NTc * Ec) / 4;
    if (j >= 0 && j < 65 * 384) {
        int d = j / 384, g = j % 384;
        gWihT[j] = gWih[(size_t)g * 65 + d];
    }
}

// ---------------------------------------------------------------
// batched tiled transpose + fp32->bf16 convert: W[K,N] -> Wt[N,K]
struct CJob { const float* src; __bf16* dst; };
struct CJobs8 { CJob j[8]; };

__global__ __launch_bounds__(256)
void convT_k(CJobs8 jobs, int K, int N)
{
    CJob J = jobs.j[blockIdx.z];
    __shared__ float t[32][33];
    int bx = blockIdx.x * 32;   // n tile
    int by = blockIdx.y * 32;   // k tile
    int tx = threadIdx.x & 31, ty = threadIdx.x >> 5;   // 32 x 8
#pragma unroll
    for (int i = 0; i < 4; ++i) {
        int k = by + ty + i * 8, n = bx + tx;
        t[ty + i * 8][tx] = (k < K && n < N) ? J.src[(size_t)k * N + n] : 0.f;
    }
    __syncthreads();
#pragma unroll
    for (int i = 0; i < 4; ++i) {
        int n = bx + ty + i * 8, k = by + tx;
        if (n < N && k < K) J.dst[(size_t)n * K + k] = (__bf16)t[tx][ty + i * 8];
    }
}

// ---------------------------------------------------------------
// router proc GEMM v2 (r11): x[2048,512] @ Wtp[512,128] + btp, relu.
// Old gemm_k ran 64 blocks (quarter-chip, 1 wave/SIMD, LDS-heavy fp32)
// est 12-17us. Now 512 blocks x 256thr, 4 tokens/block: x tile staged
// in LDS (broadcast reads), Wtp[k*128+j] coalesced. Accumulation is
// k-ascending FMA with bias added LAST — bit-identical to gemm_k
// (routing stability preserved).
__global__ __launch_bounds__(256)
void proc_k(const float* __restrict__ x, const float* __restrict__ Wtp,
            const float* __restrict__ btp, float* __restrict__ proc)
{
    int b = blockIdx.x, tid = threadIdx.x;
    int j = tid & 127, half = tid >> 7;      // col, token-pair select
    __shared__ float xs[4 * Ec];
    const float4* src = (const float4*)(x + (size_t)b * 4 * Ec);
    ((float4*)xs)[tid] = src[tid];
    ((float4*)xs)[256 + tid] = src[256 + tid];
    __syncthreads();
    const float* x0 = xs + (half * 2) * Ec;
    const float* x1 = xs + (half * 2 + 1) * Ec;
    float a0 = 0.f, a1 = 0.f;
#pragma unroll 8
    for (int k = 0; k < Ec; ++k) {
        float wv = Wtp[(size_t)k * Pc + j];
        a0 += x0[k] * wv;
        a1 += x1[k] * wv;
    }
    int t0 = b * 4 + half * 2;
    proc[(size_t)t0 * Pc + j]       = fmaxf(a0 + btp[j], 0.f);
    proc[(size_t)(t0 + 1) * Pc + j] = fmaxf(a1 + btp[j], 0.f);
}

// q4 GEMM v2: proc[2048,128] @ Wq[128,64] + bq. Same bit-stability rules.
__global__ __launch_bounds__(256)
void q4_k(const float* __restrict__ proc, const float* __restrict__ Wq,
          const float* __restrict__ bq, float* __restrict__ q4)
{
    int b = blockIdx.x, tid = threadIdx.x;
    int j = tid & 63, tk = tid >> 6;         // col, token 0..3
    __shared__ float pr[4 * Pc];
    const float2* src = (const float2*)(proc + (size_t)b * 4 * Pc);
    ((float2*)pr)[tid] = src[tid];
    __syncthreads();
    const float* p = pr + tk * Pc;
    float a = 0.f;
#pragma unroll 8
    for (int k = 0; k < Pc; ++k) a += p[k] * Wq[(size_t)k * AKc + j];
    q4[(size_t)(b * 4 + tk) * AKc + j] = a + bq[j];
}

// ---------------------------------------------------------------
// batched bf16 MFMA GEMM with optional split-K.
// flags: 1=relu, 2=storeT, 4=storeBf, 8=atomicAccum(fp32 C).
struct GJob {
    const void* A;
    const void* B;
    const float* bias;
    void* C;
    const int* Mptr;
    const int* gatherA;
    float* scatterOut;
    const int* scatterList;
    const float* wvec;
    int ldc;
    int flags;
};
struct GJobs6 { GJob j[6]; };

#define LDA_S 40   // LDS row stride in bf16 elems (32 + 8 pad)
template<int AMODE>
__global__ __launch_bounds__(256)
void gemm_batch_k(GJobs6 jobs, int lda, int ldb, int N, int K,
                  int nTilesY, int kIters)
{
    GJob J = jobs.j[blockIdx.z];
    int M = *J.Mptr;
    int by = blockIdx.y;
    int ny = by % nTilesY, ko = by / nTilesY;
    int tm = blockIdx.x * 128, tn = ny * 128;
    if (tm >= M || tn >= N) return;
    int KT = K / 32;
    int kt0 = ko * kIters;
    int ktE = kt0 + kIters; if (ktE > KT) ktE = KT;
    if (kt0 >= KT) return;

    __shared__ __bf16 As[128 * LDA_S];
    __shared__ __bf16 Bs[128 * LDA_S];
    int tid = threadIdx.x, lane = tid & 63, wvi = tid >> 6;
    int wm = (wvi & 1) * 64, wn = (wvi >> 1) * 64;
    f32x4 acc[4][4] = {};

    int ar = tid >> 1, ah = (tid & 1) * 16;   // staging row / k-half
    const float*  Apf = nullptr;
    const __bf16* Apb = nullptr;
    if (tm + ar < M) {
        int g = J.gatherA ? J.gatherA[tm + ar] : (tm + ar);
        if (AMODE == 0) Apf = (const float*)J.A + (size_t)g * lda;
        else            Apb = (const __bf16*)J.A + (size_t)g * lda;
    }
    const __bf16* Bp = ((tn + ar) < N) ? ((const __bf16*)J.B + (size_t)(tn + ar) * ldb)
                                       : nullptr;

    float fa[16];
    bfv8 ra0, ra1, rb0, rb1;

    auto LOADA = [&](int k0) {
        int kb = k0 + ah;
        if (AMODE == 0) {
            if (Apf) {
                const float4* p = (const float4*)(Apf + kb);
                float4 x0 = p[0], x1 = p[1], x2 = p[2], x3 = p[3];
                fa[0]=x0.x; fa[1]=x0.y; fa[2]=x0.z; fa[3]=x0.w;
                fa[4]=x1.x; fa[5]=x1.y; fa[6]=x1.z; fa[7]=x1.w;
                fa[8]=x2.x; fa[9]=x2.y; fa[10]=x2.z; fa[11]=x2.w;
                fa[12]=x3.x; fa[13]=x3.y; fa[14]=x3.z; fa[15]=x3.w;
            } else {
#pragma unroll
                for (int i = 0; i < 16; ++i) fa[i] = 0.f;
            }
        } else {
            if (Apb) {
                ra0 = *(const bfv8*)(Apb + kb);
                ra1 = *(const bfv8*)(Apb + kb + 8);
            } else {
#pragma unroll
                for (int i = 0; i < 8; ++i) { ra0[i] = (__bf16)0.f; ra1[i] = (__bf16)0.f; }
            }
        }
    };
    auto LOADB = [&](int k0) {
        int kb = k0 + ah;
        if (Bp) {
            rb0 = *(const bfv8*)(Bp + kb);
            rb1 = *(const bfv8*)(Bp + kb + 8);
        } else {
#pragma unroll
            for (int i = 0; i < 8; ++i) { rb0[i] = (__bf16)0.f; rb1[i] = (__bf16)0.f; }
        }
    };

    LOADA(kt0 * 32);
    LOADB(kt0 * 32);

    for (int kt = kt0; kt < ktE; ++kt) {
        __syncthreads();
        if (AMODE == 0) {
            bfv8 p0, p1;
#pragma unroll
            for (int i = 0; i < 8; ++i) { p0[i] = (__bf16)fa[i]; p1[i] = (__bf16)fa[8 + i]; }
            *(bfv8*)(As + ar * LDA_S + ah) = p0;
            *(bfv8*)(As + ar * LDA_S + ah + 8) = p1;
        } else {
            *(bfv8*)(As + ar * LDA_S + ah) = ra0;
            *(bfv8*)(As + ar * LDA_S + ah + 8) = ra1;
        }
        *(bfv8*)(Bs + ar * LDA_S + ah) = rb0;
        *(bfv8*)(Bs + ar * LDA_S + ah + 8) = rb1;
        __syncthreads();
        if (kt + 1 < ktE) {
            LOADA((kt + 1) * 32);
            LOADB((kt + 1) * 32);
        }
        {
            int fr = lane & 15, quad = lane >> 4;
            bfv8 af[4], bfr[4];
            const __bf16* Ab = As + quad * 8 + fr * LDA_S;
            const __bf16* Bb2 = Bs + quad * 8 + fr * LDA_S;
#pragma unroll
            for (int t2 = 0; t2 < 4; ++t2) {
                af[t2]  = *(const bfv8*)(Ab + (wm + t2 * 16) * LDA_S);
                bfr[t2] = *(const bfv8*)(Bb2 + (wn + t2 * 16) * LDA_S);
            }
#pragma unroll
            for (int i = 0; i < 4; ++i)
#pragma unroll
                for (int j = 0; j < 4; ++j)
                    acc[i][j] = __builtin_amdgcn_mfma_f32_16x16x32_bf16(af[i], bfr[j], acc[i][j], 0, 0, 0);
        }
    }

    // epilogue: C layout col=lane&15, row=(lane>>4)*4+reg
    int col = lane & 15, rq = (lane >> 4) * 4;
    int relu = J.flags & 1, storeT = J.flags & 2, storeBf = J.flags & 4;
    int accum = J.flags & 8;
    int addBias = (J.bias != nullptr) && (ko == 0);
#pragma unroll
    for (int ti = 0; ti < 4; ++ti) {
#pragma unroll
        for (int tj = 0; tj < 4; ++tj) {
#pragma unroll
            for (int r = 0; r < 4; ++r) {
                int gm = tm + wm + ti * 16 + rq + r;
                int gn = tn + wn + tj * 16 + col;
                if (gm < M && gn < N) {
                    float v = acc[ti][tj][r] + (addBias ? J.bias[gn] : 0.f);
                    if (relu) v = fmaxf(v, 0.f);
                    if (J.scatterOut) {
                        int g = J.scatterList[gm];
                        atomicAdd(&J.scatterOut[(size_t)g * Ec + gn], v * J.wvec[(size_t)g * NEc]);
                    } else if (accum) {
                        atomicAdd(&((float*)J.C)[(size_t)gm * J.ldc + gn], v);
                    } else if (storeT) {
                        ((float*)J.C)[(size_t)gn * J.ldc + gm] = v;
                    } else if (storeBf) {
                        ((__bf16*)J.C)[(size_t)gm * J.ldc + gn] = (__bf16)v;
                    } else {
                        ((float*)J.C)[(size_t)gm * J.ldc + gn] = v;
                    }
                }
            }
        }
    }
}

// ---------------------------------------------------------------
// Flash attention over compacted tokens, batched over experts (blockIdx.z).
__global__ __launch_bounds__(256)
void flash_k(const float* __restrict__ QbB, const float* __restrict__ KbB,
             const float* __restrict__ VtB, float* __restrict__ AOB,
             const int* __restrict__ cntB)
{
    int e = blockIdx.z;
    const float* Qb = QbB + (size_t)e * NTc * Ec;
    const float* Kb = KbB + (size_t)e * NTc * Ec;
    const float* Vt = VtB + (size_t)e * NTc * Ec;
    float* AO = AOB + (size_t)e * NTc * Ec;
    int nv = cntB[e];
    int r0 = blockIdx.x * 64;
    if (r0 >= nv) return;
    int h = blockIdx.y;
    const int QS = 136, VS = 72;
    __shared__ __bf16 Ql[64 * 136];
    __shared__ __bf16 Kl[64 * 136];
    __shared__ __bf16 Vl[128 * 72];
    __shared__ __bf16 Pl[64 * 72];
    int tid = threadIdx.x, lane = tid & 63, wv = tid >> 6;
    int fr = lane & 15, quad = lane >> 4;

    {   // load Q tile (rows >= nv -> 0)
        int qr = tid >> 2, c0 = (tid & 3) * 32;
        const float* src = Qb + (size_t)(r0 + qr) * Ec + h * HDc + c0;
        __bf16* dst = Ql + qr * QS + c0;
        bool ok = (r0 + qr) < nv;
#pragma unroll
        for (int u = 0; u < 8; ++u) {
            float4 v = ok ? ((const float4*)src)[u] : make_float4(0.f, 0.f, 0.f, 0.f);
            dst[u*4+0] = (__bf16)v.x; dst[u*4+1] = (__bf16)v.y;
            dst[u*4+2] = (__bf16)v.z; dst[u*4+3] = (__bf16)v.w;
        }
    }

    f32x4 accO[8];
#pragma unroll
    for (int j = 0; j < 8; ++j) accO[j] = (f32x4){0.f, 0.f, 0.f, 0.f};
    float mrow[4] = {-1e30f, -1e30f, -1e30f, -1e30f};
    float lrow[4] = {0.f, 0.f, 0.f, 0.f};
    const float invsq = 0.08838834764831845f;   // 1/sqrt(128)

    for (int j0 = 0; j0 < nv; j0 += 64) {
        __syncthreads();
        {   // K tile
            int kr = tid >> 2, c0 = (tid & 3) * 32;
            const float* src = Kb + (size_t)(j0 + kr) * Ec + h * HDc + c0;
            __bf16* dst = Kl + kr * QS + c0;
            bool ok = (j0 + kr) < nv;
#pragma unroll
            for (int u = 0; u < 8; ++u) {
                float4 v = ok ? ((const float4*)src)[u] : make_float4(0.f, 0.f, 0.f, 0.f);
                dst[u*4+0] = (__bf16)v.x; dst[u*4+1] = (__bf16)v.y;
                dst[u*4+2] = (__bf16)v.z; dst[u*4+3] = (__bf16)v.w;
            }
        }
        {   // Vt tile (d-major)
            int dr = tid >> 1, c0 = (tid & 1) * 32;
            const float* src = Vt + (size_t)(h * HDc + dr) * NTc + j0 + c0;
            __bf16* dst = Vl + dr * VS + c0;
            int rem = nv - (j0 + c0);
            if (rem >= 32) {
#pragma unroll
                for (int u = 0; u < 8; ++u) {
                    float4 v = ((const float4*)src)[u];
                    dst[u*4+0] = (__bf16)v.x; dst[u*4+1] = (__bf16)v.y;
                    dst[u*4+2] = (__bf16)v.z; dst[u*4+3] = (__bf16)v.w;
                }
            } else {
                for (int u = 0; u < 32; ++u)
                    dst[u] = (u < rem) ? (__bf16)src[u] : (__bf16)0.f;
            }
        }
        __syncthreads();

        // S = Q K^T (wave owns rows wv*16..+16)
        f32x4 sc[4] = {};
#pragma unroll
        for (int ks = 0; ks < 4; ++ks) {
            bfv8 aq = *(const bfv8*)(Ql + (wv * 16 + fr) * QS + ks * 32 + quad * 8);
#pragma unroll
            for (int tj = 0; tj < 4; ++tj) {
                bfv8 bk8 = *(const bfv8*)(Kl + (tj * 16 + fr) * QS + ks * 32 + quad * 8);
                sc[tj] = __builtin_amdgcn_mfma_f32_16x16x32_bf16(aq, bk8, sc[tj], 0, 0, 0);
            }
        }

        float alpha[4];
#pragma unroll
        for (int r = 0; r < 4; ++r) {
            float sv[4];
            float mx = -1e30f;
#pragma unroll
            for (int tj = 0; tj < 4; ++tj) {
                float s = sc[tj][r] * invsq;
                bool valid = (j0 + tj * 16 + fr) < nv;
                s = valid ? s : -1e30f;
                sv[tj] = s;
                mx = fmaxf(mx, s);
            }
#pragma unroll
            for (int off = 1; off < 16; off <<= 1)
                mx = fmaxf(mx, __shfl_xor(mx, off, 64));
            float mn = fmaxf(mrow[r], mx);
            alpha[r] = expf(mrow[r] - mn);
            float ps = 0.f;
#pragma unroll
            for (int tj = 0; tj < 4; ++tj) {
                bool valid = (j0 + tj * 16 + fr) < nv;
                float p = valid ? expf(sv[tj] - mn) : 0.f;
                Pl[(wv * 16 + quad * 4 + r) * VS + tj * 16 + fr] = (__bf16)p;
                ps += p;
            }
#pragma unroll
            for (int off = 1; off < 16; off <<= 1)
                ps += __shfl_xor(ps, off, 64);
            lrow[r] = lrow[r] * alpha[r] + ps;
            mrow[r] = mn;
        }
#pragma unroll
        for (int tj = 0; tj < 8; ++tj)
#pragma unroll
            for (int r = 0; r < 4; ++r)
                accO[tj][r] *= alpha[r];
        // PV (P per-wave LDS region -> A frag; within-wave, no barrier)
#pragma unroll
        for (int ks = 0; ks < 2; ++ks) {
            bfv8 ap = *(const bfv8*)(Pl + (wv * 16 + fr) * VS + ks * 32 + quad * 8);
#pragma unroll
            for (int tj = 0; tj < 8; ++tj) {
                bfv8 bv8 = *(const bfv8*)(Vl + (tj * 16 + fr) * VS + ks * 32 + quad * 8);
                accO[tj] = __builtin_amdgcn_mfma_f32_16x16x32_bf16(ap, bv8, accO[tj], 0, 0, 0);
            }
        }
    }

#pragma unroll
    for (int r = 0; r < 4; ++r) {
        int row = r0 + wv * 16 + quad * 4 + r;
        if (row < nv) {
            float invl = 1.f / lrow[r];
#pragma unroll
            for (int tj = 0; tj < 8; ++tj)
                AO[(size_t)row * Ec + h * HDc + tj * 16 + fr] = accO[tj][r] * invl;
        }
    }
}

// ---------------------------------------------------------------
__global__ __launch_bounds__(256)
void router_ctx_k(const float* __restrict__ q4, const float* __restrict__ rR,
                  const float* __restrict__ rS,
                  const float* __restrict__ Wk, const float* __restrict__ bk,
                  const float* __restrict__ Wv, const float* __restrict__ bv,
                  float* __restrict__ ctx)
{
    int tid = threadIdx.x;
    int lane = tid & 63;
    int n = blockIdx.x * 4 + (tid >> 6);
    int m = (n >> 7) & 3, t = n & 127, b = n >> 9;
    float q = q4[(size_t)n * AKc + lane];
    float sc[3], rv[3], sv[3];
#pragma unroll
    for (int o = 0; o < 3; ++o) {
        int oth = o + (o >= m ? 1 : 0);
        float r = rR[(((size_t)(b * Mc + m)) * Mc + oth) * Tc + t];
        float s_ = rS[(((size_t)(b * Mc + m)) * Mc + oth) * Tc + t];
        rv[o] = r; sv[o] = s_;
        float key = r * Wk[lane] + s_ * Wk[64 + lane] + bk[lane];
        float p = q * key;
#pragma unroll
        for (int off = 32; off; off >>= 1) p += __shfl_xor(p, off, 64);
        sc[o] = p * 0.125f;
    }
    float mx = fmaxf(sc[0], fmaxf(sc[1], sc[2]));
    float e0 = expf(sc[0] - mx), e1 = expf(sc[1] - mx), e2 = expf(sc[2] - mx);
    float inv = 1.f / (e0 + e1 + e2);
    float p0 = e0 * inv, p1 = e1 * inv, p2 = e2 * inv;
    float v0 = rv[0] * Wv[lane] + sv[0] * Wv[64 + lane] + bv[lane];
    float v1 = rv[1] * Wv[lane] + sv[1] * Wv[64 + lane] + bv[lane];
    float v2 = rv[2] * Wv[lane] + sv[2] * Wv[64 + lane] + bv[lane];
    ctx[(size_t)n * AVc + lane] = p0 * v0 + p1 * v1 + p2 * v2;
}

// ---------------------------------------------------------------
// gi_k v2: coalesced weight access via pre-transposed WT[65][384]
// (r9 win: 935.7 -> 913.4us). Accumulation order identical to v1.
__global__ __launch_bounds__(384)
void gi_k(const float* __restrict__ rU, const float* __restrict__ ctx,
          const float* __restrict__ WT, const float* __restrict__ gbih,
          float* __restrict__ gi)
{
    int nt = blockIdx.x;            // 2048
    int g = threadIdx.x;            // 384
    __shared__ float cl[64];
    if (g < 64) cl[g] = ctx[(size_t)nt * AVc + g];
    __syncthreads();
    float a = gbih[g] + rU[nt] * WT[g];
#pragma unroll
    for (int d = 0; d < 64; ++d) a += cl[d] * WT[(size_t)(1 + d) * 384 + g];
    gi[(size_t)nt * 384 + g] = a;
}

// ---------------------------------------------------------------
// GRU scan — FROZEN at the r7 version (best measured: 114us).
__device__ __forceinline__ void wgbar()
{
    __builtin_amdgcn_sched_barrier(0);
    asm volatile("s_waitcnt lgkmcnt(0)" ::: "memory");
    __builtin_amdgcn_s_barrier();
    __builtin_amdgcn_sched_barrier(0);
}

__global__ __launch_bounds__(1024) __attribute__((amdgpu_waves_per_eu(4, 4)))
void gru_scan_k(const float* __restrict__ gi, const float* __restrict__ gWhh,
                const float* __restrict__ gbhh, float* __restrict__ hs)
{
    int seq = blockIdx.x, tid = threadIdx.x;
    int work = (tid < 768);
    int g = work ? (tid >> 1) : 0;           // output g (safe for idle waves)
    int half = tid & 1;                      // K-half
    __shared__ float h[136];                 // [0..63] half0, [68..131] half1
    __shared__ float gh[384];
    const f32x4* wp = (const f32x4*)(gWhh + (size_t)g * 128 + half * 64);
    f32x4 w0 = wp[0],  w1 = wp[1],  w2 = wp[2],  w3 = wp[3];
    f32x4 w4 = wp[4],  w5 = wp[5],  w6 = wp[6],  w7 = wp[7];
    f32x4 w8 = wp[8],  w9 = wp[9],  wA = wp[10], wB = wp[11];
    f32x4 wC = wp[12], wD = wp[13], wE = wp[14], wF = wp[15];
    float bh = gbhh[g];

    // gate state (threads 0..127 = waves 0,1)
    float hreg = 0.f, c0 = 0.f, c1 = 0.f, c2 = 0.f;
    int hi = tid + ((tid >> 6) << 2);        // tid<64 -> tid; 64..127 -> tid+4
    if (tid < 128) {
        h[hi] = 0.f;
        const float* gr = gi + (size_t)seq * 128 * 384;
        c0 = gr[tid]; c1 = gr[128 + tid]; c2 = gr[256 + tid];
    }
    wgbar();

    for (int t = 0; t < 128; ++t) {
        // keep weights resident: 4-reg vector granules, pinned every iter
        asm volatile("" : "+v"(w0), "+v"(w1), "+v"(w2), "+v"(w3),
                          "+v"(w4), "+v"(w5), "+v"(w6), "+v"(w7),
                          "+v"(w8), "+v"(w9), "+v"(wA), "+v"(wB),
                          "+v"(wC), "+v"(wD), "+v"(wE), "+v"(wF));
        // prefetch gi row for t+1 — full matvec of latency cover
        float n0 = 0.f, n1 = 0.f, n2 = 0.f;
        if (tid < 128 && t + 1 < 128) {
            const float* gr = gi + ((size_t)seq * 128 + t + 1) * 384;
            n0 = gr[tid]; n1 = gr[128 + tid]; n2 = gr[256 + tid];
        }
        if (work) {
            // half dot product: 64 FMAs over the thread's h-half
            float a0 = 0.f, a1 = 0.f, a2 = 0.f, a3 = 0.f;
            const float* hb = h + half * 68; // conflict-free bank offset
#define GRU_STEP4(W, B) { \
            f32x4 x = *(const f32x4*)&hb[B]; \
            a0 += x[0] * W[0]; a1 += x[1] * W[1]; a2 += x[2] * W[2]; a3 += x[3] * W[3]; }
            GRU_STEP4(w0, 0)   GRU_STEP4(w1, 4)   GRU_STEP4(w2, 8)   GRU_STEP4(w3, 12)
            GRU_STEP4(w4, 16)  GRU_STEP4(w5, 20)  GRU_STEP4(w6, 24)  GRU_STEP4(w7, 28)
            GRU_STEP4(w8, 32)  GRU_STEP4(w9, 36)  GRU_STEP4(wA, 40)  GRU_STEP4(wB, 44)
            GRU_STEP4(wC, 48)  GRU_STEP4(wD, 52)  GRU_STEP4(wE, 56)  GRU_STEP4(wF, 60)
#undef GRU_STEP4
            float s = (a0 + a1) + (a2 + a3);
            s += __shfl_xor(s, 1, 64);       // combine the two K-halves
            if (half == 0) gh[g] = s + bh;
        }
        wgbar();                              // no vmcnt drain
        if (tid < 128) {
            float ghr = gh[tid], ghz = gh[128 + tid], ghn = gh[256 + tid];
            float r  = 1.f / (1.f + expf(-(c0 + ghr)));
            float z  = 1.f / (1.f + expf(-(c1 + ghz)));
            float nn = tanhf(c2 + r * ghn);
            float hn = (1.f - z) * nn + z * hreg;
            hs[((size_t)seq * 128 + t) * 128 + tid] = hn;   // fire-and-forget
            h[hi] = hn;
            hreg = hn;
            c0 = n0; c1 = n1; c2 = n2;        // vmcnt wait lands here only
        }
        wgbar();
    }
}

// ---------------------------------------------------------------
__global__ __launch_bounds__(128)
void mlp_route_k(const float* __restrict__ proc, const float* __restrict__ hs,
                 const float* __restrict__ mW1, const float* __restrict__ mb1,
                 const float* __restrict__ mW2, const float* __restrict__ mb2,
                 float* __restrict__ probsOut, float* __restrict__ idxOut,
                 float* __restrict__ w)
{
    int n = blockIdx.x, tid = threadIdx.x;
    __shared__ float comb[256], tmp[128], lg[8];
    comb[tid] = proc[(size_t)n * 128 + tid];
    comb[128 + tid] = hs[(size_t)n * 128 + tid];
    __syncthreads();
    float a = mb1[tid];
#pragma unroll 8
    for (int d = 0; d < 256; ++d) a += comb[d] * mW1[(size_t)d * 128 + tid];
    tmp[tid] = fmaxf(a, 0.f);
    __syncthreads();
    if (tid < 8) {
        float l = mb2[tid];
        for (int d = 0; d < 128; ++d) l += tmp[d] * mW2[(size_t)d * 8 + tid];
        lg[tid] = l;
    }
    __syncthreads();
    if (tid == 0) {
        float mx = lg[0];
        for (int e = 1; e < 8; ++e) mx = fmaxf(mx, lg[e]);
        float p[8], s = 0.f;
        for (int e = 0; e < 8; ++e) { p[e] = expf(lg[e] - mx); s += p[e]; }
        float inv = 1.f / s;
        for (int e = 0; e < 8; ++e) probsOut[(size_t)n * 8 + e] = p[e] * inv;
        int a0 = 0; float v0 = lg[0];
        for (int e = 1; e < 8; ++e) if (lg[e] > v0) { v0 = lg[e]; a0 = e; }
        int a1 = -1; float v1 = -1e30f;
        for (int e = 0; e < 8; ++e) if (e != a0 && lg[e] > v1) { v1 = lg[e]; a1 = e; }
        float e1 = expf(v1 - v0);
        float t0 = 1.f / (1.f + e1), t1 = e1 / (1.f + e1);
        idxOut[(size_t)n * 2 + 0] = (float)a0;
        idxOut[(size_t)n * 2 + 1] = (float)a1;
        for (int e = 0; e < 8; ++e) w[(size_t)n * 8 + e] = 0.f;
        w[(size_t)n * 8 + a0] = t0;
        w[(size_t)n * 8 + a1] = t1;
    }
}

__global__ __launch_bounds__(256)
void compact_k(const float* __restrict__ w, int* __restrict__ cnt,
               int* __restrict__ list)
{
    int n = blockIdx.x * 256 + threadIdx.x;
    if (n >= NTc) return;
    for (int e = 0; e < NEc; ++e)
        if (w[(size_t)n * 8 + e] > 0.f) {
            int p = atomicAdd(&cnt[e], 1);
            list[e * NTc + p] = n;
        }
}

// ---------------------------------------------------------------
// LN1 batched over experts (blockIdx.y): LN(x[list[i]] + PRJ[i]) -> H1[i]
__global__ __launch_bounds__(256)
void ln1_k(const float* __restrict__ x, const int* __restrict__ listB,
           const float* __restrict__ addB, const float* __restrict__ sB,
           const float* __restrict__ bB, float* __restrict__ outB,
           const int* __restrict__ cntB)
{
    int e = blockIdx.y;
    int i = blockIdx.x;
    if (i >= cntB[e]) return;
    const int* list = listB + e * NTc;
    const float* add = addB + (size_t)e * NTc * Ec;
    const float* s = sB + e * Ec;
    const float* b = bB + e * Ec;
    float* outRows = outB + (size_t)e * NTc * Ec;
    int tid = threadIdx.x;
    int g = list[i];
    float v0 = x[(size_t)g * Ec + tid] + add[(size_t)i * Ec + tid];
    float v1 = x[(size_t)g * Ec + 256 + tid] + add[(size_t)i * Ec + 256 + tid];
    __shared__ float red[256];
    __shared__ float bc;
    red[tid] = v0 + v1; __syncthreads();
    for (int st = 128; st > 0; st >>= 1) { if (tid < st) red[tid] += red[tid + st]; __syncthreads(); }
    if (tid == 0) bc = red[0] * (1.f / 512.f);
    __syncthreads();
    float mu = bc;
    float d0 = v0 - mu, d1 = v1 - mu;
    __syncthreads();
    red[tid] = d0 * d0 + d1 * d1; __syncthreads();
    for (int st = 128; st > 0; st >>= 1) { if (tid < st) red[tid] += red[tid + st]; __syncthreads(); }
    if (tid == 0) bc = rsqrtf(red[0] * (1.f / 512.f) + 1e-5f);
    __syncthreads();
    float inv = bc;
    outRows[(size_t)i * Ec + tid] = d0 * inv * s[tid] + b[tid];
    outRows[(size_t)i * Ec + 256 + tid] = d1 * inv * s[256 + tid] + b[256 + tid];
}

// LN2 batched over experts; atomic scatter (experts' token sets overlap)
__global__ __launch_bounds__(256)
void ln2_scatter_k(const float* __restrict__ H1B, const float* __restrict__ YB,
                   const float* __restrict__ sB, const float* __restrict__ bB,
                   float* __restrict__ out, const int* __restrict__ listB,
                   const int* __restrict__ cntB, const float* __restrict__ wB)
{
    int e = blockIdx.y;
    int i = blockIdx.x;
    if (i >= cntB[e]) return;
    const int* list = listB + e * NTc;
    const float* H1 = H1B + (size_t)e * NTc * Ec;
    const float* Y = YB + (size_t)e * NTc * Ec;
    const float* s = sB + e * Ec;
    const float* b = bB + e * Ec;
    const float* wvec = wB + e;
    int tid = threadIdx.x;
    int g = list[i];
    float v0 = H1[(size_t)i * Ec + tid] + Y[(size_t)i * Ec + tid];
    float v1 = H1[(size_t)i * Ec + 256 + tid] + Y[(size_t)i * Ec + 256 + tid];
    __shared__ float red[256];
    __shared__ float bc;
    red[tid] = v0 + v1; __syncthreads();
    for (int st = 128; st > 0; st >>= 1) { if (tid < st) red[tid] += red[tid + st]; __syncthreads(); }
    if (tid == 0) bc = red[0] * (1.f / 512.f);
    __syncthreads();
    float mu = bc;
    float d0 = v0 - mu, d1 = v1 - mu;
    __syncthreads();
    red[tid] = d0 * d0 + d1 * d1; __syncthreads();
    for (int st = 128; st > 0; st >>= 1) { if (tid < st) red[tid] += red[tid + st]; __syncthreads(); }
    if (tid == 0) bc = rsqrtf(red[0] * (1.f / 512.f) + 1e-5f);
    __syncthreads();
    float inv = bc;
    float wv = wvec[(size_t)g * 8];
    atomicAdd(&out[(size_t)g * Ec + tid], (d0 * inv * s[tid] + b[tid]) * wv);
    atomicAdd(&out[(size_t)g * Ec + 256 + tid], (d1 * inv * s[256 + tid] + b[256 + tid]) * wv);
}

// ---------------------------------------------------------------
extern "C" void kernel_launch(void* const* d_in, const int* in_sizes, int n_in,
                              void* d_out, int out_size, void* d_ws, size_t ws_size,
                              hipStream_t stream)
{
    const float* x    = (const float*)d_in[0];
    const float* rU   = (const float*)d_in[1];
    const float* rR   = (const float*)d_in[2];
    const float* rS   = (const float*)d_in[3];
    const float* Wtp  = (const float*)d_in[6];
    const float* btp  = (const float*)d_in[7];
    const float* Wq   = (const float*)d_in[8];
    const float* bq   = (const float*)d_in[9];
    const float* Wk   = (const float*)d_in[10];
    const float* bk   = (const float*)d_in[11];
    const float* Wv   = (const float*)d_in[12];
    const float* bv   = (const float*)d_in[13];
    const float* gWih = (const float*)d_in[14];
    const float* gbih = (const float*)d_in[15];
    const float* gWhh = (const float*)d_in[16];
    const float* gbhh = (const float*)d_in[17];
    const float* mW1  = (const float*)d_in[18];
    const float* mb1  = (const float*)d_in[19];
    const float* mW2  = (const float*)d_in[20];
    const float* mb2  = (const float*)d_in[21];
    const float* sWq  = (const float*)d_in[22];
    const float* sbq  = (const float*)d_in[23];
    const float* sWk  = (const float*)d_in[24];
    const float* sbk  = (const float*)d_in[25];
    const float* sWv  = (const float*)d_in[26];
    const float* sbv  = (const float*)d_in[27];
    const float* sWo  = (const float*)d_in[28];
    const float* sbo  = (const float*)d_in[29];
    const float* sln1s = (const float*)d_in[30];
    const float* sln1b = (const float*)d_in[31];
    const float* sW1  = (const float*)d_in[32];
    const float* sb1  = (const float*)d_in[33];
    const float* sW2  = (const float*)d_in[34];
    const float* sb2  = (const float*)d_in[35];
    const float* sln2s = (const float*)d_in[36];
    const float* sln2b = (const float*)d_in[37];
    const float* fW1  = (const float*)d_in[38];
    const float* fb1  = (const float*)d_in[39];
    const float* fW2  = (const float*)d_in[40];
    const float* fb2  = (const float*)d_in[41];

    float* out      = (float*)d_out;                 // [2048,512]
    float* probsOut = out + (size_t)NTc * Ec;        // [2048,8]
    float* idxOut   = probsOut + (size_t)NTc * NEc;  // [2048,2]

    // ---- workspace layout ----
    int*   cnt  = (int*)d_ws;                        // 64 ints
    int*   list = cnt + 64;                          // 8*2048
    float* w    = (float*)d_ws + 64 + NEc * NTc;     // [2048,8]
    __bf16* WB = (__bf16*)(w + NTc * NEc);
    auto QKVO_T = [&](int e, int i) { return WB + ((size_t)(e * 4 + i)) * 262144; };
    __bf16* sW1T = WB + 8 * 262144;            // 2 x [2048][512]
    __bf16* sW2T = sW1T + 2 * 1048576;         // 2 x [512][2048]
    __bf16* fW1T = sW2T + 2 * 1048576;         // 3 x [2048][512] (round 1)
    __bf16* fW2T = fW1T + 3 * 1048576;         // 3 x [512][2048] (round 1)
    float* act = (float*)(fW2T + 3 * 1048576);
    float* QbB = act;                          // 2 x [2048][512]
    float* KbB = act + 2 * 1048576;            // 2 x
    float* VtB = act + 4 * 1048576;            // 2 x [512][2048] d-major
    float* AOB = act + 6 * 1048576;            // 2 x
    float* H1B = act + 8 * 1048576;            // 2 x
    float* PRJB = QbB;                         // alias (Qb dead after flash)
    float* YbB  = KbB;                         // alias (Kb dead after flash)
    __bf16* FF1syn = (__bf16*)VtB;             // 2 x [2048][2048] bf16 (Vt/AO dead)
    __bf16* FF1ffn = (__bf16*)act;             // 3 x [2048][2048] bf16 (FFN phase)
    // round-2 FFN weights live in the act tail (free once synergy is done):
    __bf16* fW1T2 = FF1ffn + (size_t)3 * NTc * Hc;   // 3 x [2048][512]
    __bf16* fW2T2 = fW1T2 + 3 * 1048576;             // 3 x [512][2048]
    // router region overlays act (dead before experts start)
    float* proc = act;                 // 2048*128
    float* q4   = act + 262144;
    float* ctx  = act + 393216;
    float* gi   = act + 524288;        // 16*128*384
    float* hs   = act + 1310720;       // 2048*128
    float* gWihT = act + 1572864;      // [65][384] fp32 (dead region during router)

    // ---- init (zero + gWih transpose fused) ----
    zero_k<<<1122, 256, 0, stream>>>(out, cnt, gWih, gWihT);

    // ---- router (fp32 — keeps top-2 idx bit-stable; k-ascending FMA) ----
    proc_k<<<512, 256, 0, stream>>>(x, Wtp, btp, proc);
    q4_k<<<512, 256, 0, stream>>>(proc, Wq, bq, q4);
    router_ctx_k<<<512, 256, 0, stream>>>(q4, rR, rS, Wk, bk, Wv, bv, ctx);
    gi_k<<<2048, 384, 0, stream>>>(rU, ctx, gWihT, gbih, gi);
    gru_scan_k<<<16, 1024, 0, stream>>>(gi, gWhh, gbhh, hs);
    mlp_route_k<<<2048, 128, 0, stream>>>(proc, hs, mW1, mb1, mW2, mb2,
                                          probsOut, idxOut, w);
    compact_k<<<8, 256, 0, stream>>>(w, cnt, list);

    GJob JZ = {};

    // ---- synergy weight conversion (3 dispatches) ----
    {
        CJobs8 cq = {};
        for (int e = 0; e < 2; ++e) {
            cq.j[e * 4 + 0] = { sWq + (size_t)e * Ec * Ec, QKVO_T(e, 0) };
            cq.j[e * 4 + 1] = { sWk + (size_t)e * Ec * Ec, QKVO_T(e, 1) };
            cq.j[e * 4 + 2] = { sWv + (size_t)e * Ec * Ec, QKVO_T(e, 2) };
            cq.j[e * 4 + 3] = { sWo + (size_t)e * Ec * Ec, QKVO_T(e, 3) };
        }
        convT_k<<<dim3(16, 16, 8), 256, 0, stream>>>(cq, Ec, Ec);
        CJobs8 c1 = {};
        c1.j[0] = { sW1, sW1T };
        c1.j[1] = { sW1 + (size_t)Ec * Hc, sW1T + 1048576 };
        convT_k<<<dim3(64, 16, 2), 256, 0, stream>>>(c1, Ec, Hc);
        CJobs8 c2 = {};
        c2.j[0] = { sW2, sW2T };
        c2.j[1] = { sW2 + (size_t)Hc * Ec, sW2T + 1048576 };
        convT_k<<<dim3(16, 64, 2), 256, 0, stream>>>(c2, Hc, Ec);
    }

    // ---- QKV for both experts: one 6-job dispatch ----
    {
        GJobs6 js = {};
        for (int e = 0; e < 2; ++e) {
            GJob jq = JZ;
            jq.A = x; jq.Mptr = cnt + e; jq.gatherA = list + e * NTc;
            jq.B = QKVO_T(e, 0); jq.bias = sbq + e * Ec;
            jq.C = QbB + (size_t)e * NTc * Ec; jq.ldc = Ec; jq.flags = 0;
            GJob jk = jq; jk.B = QKVO_T(e, 1); jk.bias = sbk + e * Ec;
            jk.C = KbB + (size_t)e * NTc * Ec;
            GJob jv = jq; jv.B = QKVO_T(e, 2); jv.bias = sbv + e * Ec;
            jv.C = VtB + (size_t)e * NTc * Ec; jv.ldc = NTc; jv.flags = 2;
            js.j[e * 3 + 0] = jq; js.j[e * 3 + 1] = jk; js.j[e * 3 + 2] = jv;
        }
        gemm_batch_k<0><<<dim3(16, 4, 6), 256, 0, stream>>>(js, Ec, Ec, Ec, Ec, 4, 16);
    }

    // ---- flash attention, both experts ----
    flash_k<<<dim3(32, 4, 2), 256, 0, stream>>>(QbB, KbB, VtB, AOB, cnt);

    // ---- Wo projection, both experts (r9 form) ----
    {
        GJobs6 js = {};
        for (int e = 0; e < 2; ++e) {
            GJob jo = JZ;
            jo.A = AOB + (size_t)e * NTc * Ec; jo.Mptr = cnt + e;
            jo.B = QKVO_T(e, 3); jo.bias = sbo + e * Ec;
            jo.C = PRJB + (size_t)e * NTc * Ec; jo.ldc = Ec;
            js.j[e] = jo;
        }
        gemm_batch_k<0><<<dim3(16, 4, 2), 256, 0, stream>>>(js, Ec, Ec, Ec, Ec, 4, 16);
    }

    // ---- LN1, both experts ----
    ln1_k<<<dim3(2048, 2), 256, 0, stream>>>(x, list, PRJB, sln1s, sln1b, H1B, cnt);

    // ---- FF1 (relu, bf16 out), both experts ----
    {
        GJobs6 js = {};
        for (int e = 0; e < 2; ++e) {
            GJob j1 = JZ;
            j1.A = H1B + (size_t)e * NTc * Ec; j1.Mptr = cnt + e;
            j1.B = sW1T + (size_t)e * 1048576; j1.bias = sb1 + (size_t)e * Hc;
            j1.C = FF1syn + (size_t)e * NTc * Hc; j1.ldc = Hc; j1.flags = 1 | 4;
            js.j[e] = j1;
        }
        gemm_batch_k<0><<<dim3(16, 16, 2), 256, 0, stream>>>(js, Ec, Ec, Hc, Ec, 16, 16);
    }

    // ---- FF2 (bf16 A), both experts (r9 form) ----
    {
        GJobs6 js = {};
        for (int e = 0; e < 2; ++e) {
            GJob j2 = JZ;
            j2.A = FF1syn + (size_t)e * NTc * Hc; j2.Mptr = cnt + e;
            j2.B = sW2T + (size_t)e * 1048576; j2.bias = sb2 + (size_t)e * Ec;
            j2.C = YbB + (size_t)e * NTc * Ec; j2.ldc = Ec;
            js.j[e] = j2;
        }
        gemm_batch_k<1><<<dim3(16, 4, 2), 256, 0, stream>>>(js, Hc, Hc, Ec, Hc, 4, 64);
    }

    // ---- LN2 + weighted scatter (atomic), both experts ----
    ln2_scatter_k<<<dim3(2048, 2), 256, 0, stream>>>(H1B, YbB, sln2s, sln2b,
                                                     out, list, cnt, w);

    // ---- FFN experts: all 6 weight conversions upfront (2 dispatches) ----
    {
        CJobs8 a = {};
        for (int u = 0; u < 6; ++u)
            a.j[u] = { fW1 + (size_t)u * Ec * Hc,
                       (u < 3 ? fW1T + (size_t)u * 1048576
                              : fW1T2 + (size_t)(u - 3) * 1048576) };
        convT_k<<<dim3(64, 16, 6), 256, 0, stream>>>(a, Ec, Hc);
        CJobs8 b = {};
        for (int u = 0; u < 6; ++u)
            b.j[u] = { fW2 + (size_t)u * Hc * Ec,
                       (u < 3 ? fW2T + (size_t)u * 1048576
                              : fW2T2 + (size_t)(u - 3) * 1048576) };
        convT_k<<<dim3(16, 64, 6), 256, 0, stream>>>(b, Hc, Ec);
    }

    // ---- FFN GEMMs: 2 rounds of 3 ----
    for (int rnd = 0; rnd < 2; ++rnd) {
        int f0 = rnd * 3;
        __bf16* W1 = rnd == 0 ? fW1T : fW1T2;
        __bf16* W2 = rnd == 0 ? fW2T : fW2T2;
        {
            GJobs6 js = {};
            for (int u = 0; u < 3; ++u) {
                int f = f0 + u, e = f + NSc;
                GJob j1 = JZ;
                j1.A = x; j1.Mptr = cnt + e; j1.gatherA = list + e * NTc;
                j1.B = W1 + (size_t)u * 1048576; j1.bias = fb1 + (size_t)f * Hc;
                j1.C = FF1ffn + (size_t)u * NTc * Hc; j1.ldc = Hc; j1.flags = 1 | 4;
                js.j[u] = j1;
            }
            gemm_batch_k<0><<<dim3(16, 16, 3), 256, 0, stream>>>(js, Ec, Ec, Hc, Ec, 16, 16);
        }
        {
            // FF2 scatter with split-K: 4 chunks of 16 k-iters (K=2048)
            GJobs6 js = {};
            for (int u = 0; u < 3; ++u) {
                int f = f0 + u, e = f + NSc;
                GJob j2 = JZ;
                j2.A = FF1ffn + (size_t)u * NTc * Hc; j2.Mptr = cnt + e;
                j2.B = W2 + (size_t)u * 1048576; j2.bias = fb2 + (size_t)f * Ec;
                j2.scatterOut = out; j2.scatterList = list + e * NTc;
                j2.wvec = w + e; j2.ldc = Ec;
                js.j[u] = j2;
            }
            gemm_batch_k<1><<<dim3(16, 16, 3), 256, 0, stream>>>(js, Hc, Hc, Ec, Hc, 4, 16);
        }
    }
}